// Round 13
// baseline (85.035 us; speedup 1.0000x reference)
//
#include <hip/hip_runtime.h>

#define TOKENS 16384
#define EMB 4096
#define NEXP 64
#define BK 32

typedef __attribute__((ext_vector_type(8))) short short8;
typedef __attribute__((ext_vector_type(4))) float f32x4;
typedef __attribute__((ext_vector_type(4))) unsigned short ush4;

#define WP_USHORTS (3 * NEXP * EMB)        // 1.5 MB bf16 W-planes (L2-resident)
#define WP_FLOATS  (WP_USHORTS / 2)

// async global->LDS, 16B/lane; dest = wave-uniform base + lane*16
__device__ __forceinline__ void gl_lds16(const void* g, void* lds) {
    __builtin_amdgcn_global_load_lds(
        (const __attribute__((address_space(1))) void*)g,
        (__attribute__((address_space(3))) void*)lds, 16, 0, 0);
}

// fp32 -> 3x bf16, scalar (W prep): hi RN, mid/lo trunc (R7-R12 exact).
__device__ __forceinline__ void split3(float x, unsigned short& h,
                                       unsigned short& m, unsigned short& l) {
    unsigned u = __float_as_uint(x);
    unsigned r = u + 0x7FFFu + ((u >> 16) & 1u);
    float hF = __uint_as_float(r & 0xFFFF0000u);
    h = (unsigned short)(r >> 16);
    float r1 = x - hF;
    unsigned u1 = __float_as_uint(r1);
    float mF = __uint_as_float(u1 & 0xFFFF0000u);
    m = (unsigned short)(u1 >> 16);
    float r2 = r1 - mF;
    l = (unsigned short)(__float_as_uint(r2) >> 16);
}

// pair-wise split -> packed bf16 words (identical planes; v_perm packing).
__device__ __forceinline__ void split3_pair(float x0, float x1,
        unsigned& hw, unsigned& mw, unsigned& lw) {
    unsigned u0 = __float_as_uint(x0), u1 = __float_as_uint(x1);
    unsigned r0 = u0 + 0x7FFFu + ((u0 >> 16) & 1u);
    unsigned r1 = u1 + 0x7FFFu + ((u1 >> 16) & 1u);
    hw = __builtin_amdgcn_perm(r1, r0, 0x07060302u);
    float s0 = x0 - __uint_as_float(r0 & 0xFFFF0000u);
    float s1 = x1 - __uint_as_float(r1 & 0xFFFF0000u);
    unsigned v0 = __float_as_uint(s0), v1 = __float_as_uint(s1);
    mw = __builtin_amdgcn_perm(v1, v0, 0x07060302u);
    float t0 = s0 - __uint_as_float(v0 & 0xFFFF0000u);
    float t1 = s1 - __uint_as_float(v1 & 0xFFFF0000u);
    lw = __builtin_amdgcn_perm(__float_as_uint(t1), __float_as_uint(t0), 0x07060302u);
}

// 8 floats (one lane's 32-k A slice) -> three short8 MFMA fragments
__device__ __forceinline__ void build_frags(const float4& a0, const float4& a1,
        short8& H, short8& M, short8& L) {
    union { short8 v; unsigned u[4]; } h_, m_, l_;
    split3_pair(a0.x, a0.y, h_.u[0], m_.u[0], l_.u[0]);
    split3_pair(a0.z, a0.w, h_.u[1], m_.u[1], l_.u[1]);
    split3_pair(a1.x, a1.y, h_.u[2], m_.u[2], l_.u[2]);
    split3_pair(a1.z, a1.w, h_.u[3], m_.u[3], l_.u[3]);
    H = h_.v; M = m_.v; L = l_.v;
}

// prep: split W into 3 bf16 planes Wp[plane][e][k] (flat row r = plane*64+e)
__global__ __launch_bounds__(256) void split_w(const float* __restrict__ W,
                                               unsigned short* __restrict__ Wp) {
    const int i = (blockIdx.x * 256 + threadIdx.x) * 4;
    const float4 v = *reinterpret_cast<const float4*>(W + i);
    ush4 h, m, l;
#pragma unroll
    for (int e = 0; e < 4; ++e) {
        unsigned short he, me, le;
        split3(reinterpret_cast<const float*>(&v)[e], he, me, le);
        h[e] = he; m[e] = me; l[e] = le;
    }
    *reinterpret_cast<ush4*>(Wp + i) = h;
    *reinterpret_cast<ush4*>(Wp + NEXP * EMB + i) = m;
    *reinterpret_cast<ush4*>(Wp + 2 * NEXP * EMB + i) = l;
}

// Main: MFMA split-3 bf16. R12 showed flat perf vs R11 despite halved LDS /
// VALU -> latency/burst-bound under barrier lockstep with thin TLP. Fixes:
// (a) copy-free 2-deep A pipeline: two NAMED reg sets (even/odd chunk),
//     manual unroll-2; body consumes set(ks&1) into frags then reissues
//     A(ks+2) into the SAME set -> no iter-end copies (R11/R12's copies
//     forced an early vmcnt wait, capping A cover at 1 iter ~ HBM latency);
// (b) BK=32, B staged 1-ahead from L2-resident Wp (L2 lat ~250cyc << iter),
//     2 bufs = 24 KB LDS; bank spread at b128 volume floor both sides;
// (c) 3 blocks/CU (launch_bounds(256,3), S=8 -> 1024 blocks): 3 independent
//     barrier groups per CU smooth HBM demand;
// (d) no LDS epilogue: partials stored [s][tok][e] direct from accs.
// vmcnt: steady queue before wait = [A(ks)4, st(ks)3, A(ks+1)4] -> vmcnt(4);
// last two iters peeled (vmcnt(4), vmcnt(0)). Precision identical R7-R12.
#define MFMA_BLOCK(BUFC, AH0, AM0, AL0, AH1, AM1, AL1)                          \
    _Pragma("unroll")                                                           \
    for (int et = 0; et < 4; ++et) {                                            \
        const unsigned short* bp = &sB[BUFC][et * 16 + lr][lo * 8];             \
        const short8 bH = *reinterpret_cast<const short8*>(bp);                 \
        const short8 bM = *reinterpret_cast<const short8*>(bp + 64 * BK);       \
        const short8 bL = *reinterpret_cast<const short8*>(bp + 128 * BK);      \
        accH[0][et] = __builtin_amdgcn_mfma_f32_16x16x32_bf16(AH0, bH, accH[0][et], 0, 0, 0); \
        accL[0][et] = __builtin_amdgcn_mfma_f32_16x16x32_bf16(AH0, bM, accL[0][et], 0, 0, 0); \
        accL[0][et] = __builtin_amdgcn_mfma_f32_16x16x32_bf16(AM0, bH, accL[0][et], 0, 0, 0); \
        accL[0][et] = __builtin_amdgcn_mfma_f32_16x16x32_bf16(AM0, bM, accL[0][et], 0, 0, 0); \
        accL[0][et] = __builtin_amdgcn_mfma_f32_16x16x32_bf16(AH0, bL, accL[0][et], 0, 0, 0); \
        accL[0][et] = __builtin_amdgcn_mfma_f32_16x16x32_bf16(AL0, bH, accL[0][et], 0, 0, 0); \
        accH[1][et] = __builtin_amdgcn_mfma_f32_16x16x32_bf16(AH1, bH, accH[1][et], 0, 0, 0); \
        accL[1][et] = __builtin_amdgcn_mfma_f32_16x16x32_bf16(AH1, bM, accL[1][et], 0, 0, 0); \
        accL[1][et] = __builtin_amdgcn_mfma_f32_16x16x32_bf16(AM1, bH, accL[1][et], 0, 0, 0); \
        accL[1][et] = __builtin_amdgcn_mfma_f32_16x16x32_bf16(AM1, bM, accL[1][et], 0, 0, 0); \
        accL[1][et] = __builtin_amdgcn_mfma_f32_16x16x32_bf16(AH1, bL, accL[1][et], 0, 0, 0); \
        accL[1][et] = __builtin_amdgcn_mfma_f32_16x16x32_bf16(AL1, bH, accL[1][et], 0, 0, 0); \
    }

#define BODY_MAIN(KS, AC, BUFC) do {                                            \
    asm volatile("s_waitcnt vmcnt(4)" ::: "memory");                            \
    __builtin_amdgcn_s_barrier();                                               \
    _Pragma("unroll")                                                           \
    for (int p = 0; p < 3; ++p)                                                 \
        gl_lds16(gb[p] + ((KS) + 1) * BK, &sB[(BUFC) ^ 1][48 * w + 16 * p][0]); \
    short8 aH0, aM0, aL0, aH1, aM1, aL1;                                        \
    build_frags(AC[0][0], AC[0][1], aH0, aM0, aL0);                             \
    build_frags(AC[1][0], AC[1][1], aH1, aM1, aL1);                             \
    _Pragma("unroll")                                                           \
    for (int ti = 0; ti < 2; ++ti) {                                            \
        AC[ti][0] = *reinterpret_cast<const float4*>(ax[ti] + ((KS) + 2) * BK);     \
        AC[ti][1] = *reinterpret_cast<const float4*>(ax[ti] + ((KS) + 2) * BK + 4); \
    }                                                                           \
    __builtin_amdgcn_sched_barrier(0);                                          \
    MFMA_BLOCK(BUFC, aH0, aM0, aL0, aH1, aM1, aL1)                              \
} while (0)

template<int S>
__global__ __launch_bounds__(256, 3) void router_mfma(
    const float* __restrict__ x, const unsigned short* __restrict__ Wp,
    float* __restrict__ part)
{
    constexpr int KPER = EMB / S;
    constexpr int NCH  = KPER / BK;    // even for S in {2,4,8}

    __shared__ unsigned short sB[2][192][BK];   // 24 KB

    const int t  = threadIdx.x;
    const int w  = t >> 6;     // wave 0..3
    const int l  = t & 63;
    const int lr = l & 15;     // A token-row / B expert-col
    const int lo = l >> 4;     // k-octet selector
    const int tok0 = blockIdx.x * 128 + w * 32;
    const int kb   = blockIdx.y * KPER;

    const float* ax[2];
    ax[0] = x + (size_t)(tok0 + lr) * EMB + kb + lo * 8;
    ax[1] = x + (size_t)(tok0 + 16 + lr) * EMB + kb + lo * 8;

    // B staging: wave w, p=0..2 -> rows 48w+16p..+15 (16 rows x 64 B);
    // lane l -> row +(l>>2), 16 B piece (l&3). Even 8-quad bank spread.
    const unsigned short* gb[3];
#pragma unroll
    for (int p = 0; p < 3; ++p)
        gb[p] = Wp + (size_t)(48 * w + 16 * p + (l >> 2)) * EMB + kb + 8 * (l & 3);

    f32x4 accH[2][4], accL[2][4];
#pragma unroll
    for (int ti = 0; ti < 2; ++ti)
#pragma unroll
        for (int et = 0; et < 4; ++et) {
            accH[ti][et] = (f32x4){0.f, 0.f, 0.f, 0.f};
            accL[ti][et] = (f32x4){0.f, 0.f, 0.f, 0.f};
        }

    // prologue FIFO: A(0)(4), st(0)(3), A(1)(4)  -> 11 outstanding at iter 0
    float4 aA[2][2], aB[2][2];
#pragma unroll
    for (int ti = 0; ti < 2; ++ti) {
        aA[ti][0] = *reinterpret_cast<const float4*>(ax[ti]);
        aA[ti][1] = *reinterpret_cast<const float4*>(ax[ti] + 4);
    }
#pragma unroll
    for (int p = 0; p < 3; ++p)
        gl_lds16(gb[p], &sB[0][48 * w + 16 * p][0]);
#pragma unroll
    for (int ti = 0; ti < 2; ++ti) {
        aB[ti][0] = *reinterpret_cast<const float4*>(ax[ti] + BK);
        aB[ti][1] = *reinterpret_cast<const float4*>(ax[ti] + BK + 4);
    }

#pragma unroll 1
    for (int kt = 0; kt < NCH - 2; kt += 2) {
        BODY_MAIN(kt, aA, 0);
        BODY_MAIN(kt + 1, aB, 1);
    }

    // tail ks = NCH-2 (buf 0): stage last chunk, no A-issue
    {
        asm volatile("s_waitcnt vmcnt(4)" ::: "memory");
        __builtin_amdgcn_s_barrier();
#pragma unroll
        for (int p = 0; p < 3; ++p)
            gl_lds16(gb[p] + (NCH - 1) * BK, &sB[1][48 * w + 16 * p][0]);
        short8 aH0, aM0, aL0, aH1, aM1, aL1;
        build_frags(aA[0][0], aA[0][1], aH0, aM0, aL0);
        build_frags(aA[1][0], aA[1][1], aH1, aM1, aL1);
        MFMA_BLOCK(0, aH0, aM0, aL0, aH1, aM1, aL1)
    }
    // tail ks = NCH-1 (buf 1): drain everything
    {
        asm volatile("s_waitcnt vmcnt(0)" ::: "memory");
        __builtin_amdgcn_s_barrier();
        short8 aH0, aM0, aL0, aH1, aM1, aL1;
        build_frags(aB[0][0], aB[0][1], aH0, aM0, aL0);
        build_frags(aB[1][0], aB[1][1], aH1, aM1, aL1);
        MFMA_BLOCK(1, aH0, aM0, aL0, aH1, aM1, aL1)
    }

    // epilogue: direct stores, part[s][tok][e] (4 x 64B segments / instr)
#pragma unroll
    for (int ti = 0; ti < 2; ++ti)
#pragma unroll
        for (int et = 0; et < 4; ++et)
#pragma unroll
            for (int j = 0; j < 4; ++j) {
                const int tok = tok0 + ti * 16 + lo * 4 + j;
                part[((size_t)blockIdx.y * TOKENS + tok) * NEXP + et * 16 + lr]
                    = accH[ti][et][j] + accL[ti][et][j];
            }
}

// combine splits in fp64 + bias, top-2, softmax. part layout [s][tok][e]:
// thread (slot,p4) reads 4 float4s/split, fully coalesced across lanes.
template<int S>
__global__ __launch_bounds__(256) void reduce_topk(
    const float* __restrict__ part, const float* __restrict__ b,
    float* __restrict__ out)
{
    __shared__ double sv[64][4][2];
    __shared__ int    si[64][4][2];
    const int t    = threadIdx.x;
    const int p4   = t & 3;
    const int slot = t >> 2;
    const int tok  = blockIdx.x * 64 + slot;

    double v[16];
#pragma unroll
    for (int j = 0; j < 16; ++j) v[j] = 0.0;
    for (int s = 0; s < S; ++s) {
        const float4* pp = reinterpret_cast<const float4*>(
            part + ((size_t)s * TOKENS + tok) * NEXP + (p4 << 4));
#pragma unroll
        for (int q = 0; q < 4; ++q) {
            const float4 f = pp[q];
            v[4 * q + 0] += (double)f.x;
            v[4 * q + 1] += (double)f.y;
            v[4 * q + 2] += (double)f.z;
            v[4 * q + 3] += (double)f.w;
        }
    }
#pragma unroll
    for (int j = 0; j < 16; ++j) v[j] += (double)b[(p4 << 4) + j];

    double v1 = -1e300, v2 = -1e300; int i1 = 0, i2 = 0;
#pragma unroll
    for (int j = 0; j < 16; ++j) {
        const int e = (p4 << 4) + j;
        if (v[j] > v1)      { v2 = v1; i2 = i1; v1 = v[j]; i1 = e; }
        else if (v[j] > v2) { v2 = v[j]; i2 = e; }
    }
    sv[slot][p4][0] = v1; sv[slot][p4][1] = v2;
    si[slot][p4][0] = i1; si[slot][p4][1] = i2;
    __syncthreads();

    if (p4 == 0) {
        double m1 = -1e300, m2 = -1e300; int j1 = 0, j2 = 0;
#pragma unroll
        for (int p = 0; p < 4; ++p)   // ascending parts: ties keep lowest idx
#pragma unroll
            for (int r = 0; r < 2; ++r) {
                const double vv = sv[slot][p][r]; const int ii = si[slot][p][r];
                if (vv > m1)      { m2 = m1; j2 = j1; m1 = vv; j1 = ii; }
                else if (vv > m2) { m2 = vv; j2 = ii; }
            }
        const float e2  = expf((float)(m2 - m1));   // <= 1
        const float inv = 1.0f / (1.0f + e2);
        out[2 * tok]     = (float)j1;
        out[2 * tok + 1] = (float)j2;
        out[2 * TOKENS + 2 * tok]     = inv;
        out[2 * TOKENS + 2 * tok + 1] = e2 * inv;
    }
}

extern "C" void kernel_launch(void* const* d_in, const int* in_sizes, int n_in,
                              void* d_out, int out_size, void* d_ws, size_t ws_size,
                              hipStream_t stream) {
    const float* x = (const float*)d_in[0];
    const float* W = (const float*)d_in[1];
    const float* b = (const float*)d_in[2];
    float* out = (float*)d_out;
    unsigned short* Wp = (unsigned short*)d_ws;
    float* part = (float*)d_ws + WP_FLOATS;

    split_w<<<dim3(NEXP * EMB / 1024), dim3(256), 0, stream>>>(W, Wp);

    const size_t base = (size_t)WP_FLOATS * 4;
    const size_t per  = (size_t)TOKENS * NEXP * 4;   // 4.19 MB / split
    if (ws_size >= base + 8 * per) {         // 35.1 MB -> 1024 blocks, 3-4/CU
        router_mfma<8><<<dim3(TOKENS / 128, 8), dim3(256), 0, stream>>>(x, Wp, part);
        reduce_topk<8><<<dim3(TOKENS / 64), dim3(256), 0, stream>>>(part, b, out);
    } else if (ws_size >= base + 4 * per) {  // 18.3 MB (proven)
        router_mfma<4><<<dim3(TOKENS / 128, 4), dim3(256), 0, stream>>>(x, Wp, part);
        reduce_topk<4><<<dim3(TOKENS / 64), dim3(256), 0, stream>>>(part, b, out);
    } else {
        router_mfma<2><<<dim3(TOKENS / 128, 2), dim3(256), 0, stream>>>(x, Wp, part);
        reduce_topk<2><<<dim3(TOKENS / 64), dim3(256), 0, stream>>>(part, b, out);
    }
}

// Round 14
// 76.144 us; speedup vs baseline: 1.1168x; 1.1168x over previous
//
#include <hip/hip_runtime.h>

#define TOKENS 16384
#define EMB 4096
#define NEXP 64
#define BK 32
#define KSP 4                 // in-block k-splits
#define KPER (EMB / KSP)      // 1024
#define NCH (KPER / BK)       // 32

typedef __attribute__((ext_vector_type(8))) short short8;
typedef __attribute__((ext_vector_type(4))) float f32x4;
typedef __attribute__((ext_vector_type(4))) unsigned short ush4;

#define WP_USHORTS (3 * NEXP * EMB)   // 1.5 MB bf16 W-planes (L2-resident)
#define WP_FLOATS  (WP_USHORTS / 2)

// async global->LDS, 16B/lane; dest = wave-uniform base + lane*16
__device__ __forceinline__ void gl_lds16(const void* g, void* lds) {
    __builtin_amdgcn_global_load_lds(
        (const __attribute__((address_space(1))) void*)g,
        (__attribute__((address_space(3))) void*)lds, 16, 0, 0);
}

// fp32 -> 3x bf16, scalar (W prep): hi RN, mid/lo trunc (R7-R13 exact).
__device__ __forceinline__ void split3(float x, unsigned short& h,
                                       unsigned short& m, unsigned short& l) {
    unsigned u = __float_as_uint(x);
    unsigned r = u + 0x7FFFu + ((u >> 16) & 1u);
    float hF = __uint_as_float(r & 0xFFFF0000u);
    h = (unsigned short)(r >> 16);
    float r1 = x - hF;
    unsigned u1 = __float_as_uint(r1);
    float mF = __uint_as_float(u1 & 0xFFFF0000u);
    m = (unsigned short)(u1 >> 16);
    float r2 = r1 - mF;
    l = (unsigned short)(__float_as_uint(r2) >> 16);
}

// pair-wise split -> packed bf16 words (identical planes; v_perm packing).
__device__ __forceinline__ void split3_pair(float x0, float x1,
        unsigned& hw, unsigned& mw, unsigned& lw) {
    unsigned u0 = __float_as_uint(x0), u1 = __float_as_uint(x1);
    unsigned r0 = u0 + 0x7FFFu + ((u0 >> 16) & 1u);
    unsigned r1 = u1 + 0x7FFFu + ((u1 >> 16) & 1u);
    hw = __builtin_amdgcn_perm(r1, r0, 0x07060302u);
    float s0 = x0 - __uint_as_float(r0 & 0xFFFF0000u);
    float s1 = x1 - __uint_as_float(r1 & 0xFFFF0000u);
    unsigned v0 = __float_as_uint(s0), v1 = __float_as_uint(s1);
    mw = __builtin_amdgcn_perm(v1, v0, 0x07060302u);
    float t0 = s0 - __uint_as_float(v0 & 0xFFFF0000u);
    float t1 = s1 - __uint_as_float(v1 & 0xFFFF0000u);
    lw = __builtin_amdgcn_perm(__float_as_uint(t1), __float_as_uint(t0), 0x07060302u);
}

// 8 floats (one lane's 32-k A slice) -> three short8 MFMA fragments
__device__ __forceinline__ void build_frags(const float4& a0, const float4& a1,
        short8& H, short8& M, short8& L) {
    union { short8 v; unsigned u[4]; } h_, m_, l_;
    split3_pair(a0.x, a0.y, h_.u[0], m_.u[0], l_.u[0]);
    split3_pair(a0.z, a0.w, h_.u[1], m_.u[1], l_.u[1]);
    split3_pair(a1.x, a1.y, h_.u[2], m_.u[2], l_.u[2]);
    split3_pair(a1.z, a1.w, h_.u[3], m_.u[3], l_.u[3]);
    H = h_.v; M = m_.v; L = l_.v;
}

// prep: split W into 3 bf16 planes Wp[plane][e][k] (flat row r = plane*64+e)
__global__ __launch_bounds__(256) void split_w(const float* __restrict__ W,
                                               unsigned short* __restrict__ Wp) {
    const int i = (blockIdx.x * 256 + threadIdx.x) * 4;
    const float4 v = *reinterpret_cast<const float4*>(W + i);
    ush4 h, m, l;
#pragma unroll
    for (int e = 0; e < 4; ++e) {
        unsigned short he, me, le;
        split3(reinterpret_cast<const float*>(&v)[e], he, me, le);
        h[e] = he; m[e] = me; l[e] = le;
    }
    *reinterpret_cast<ush4*>(Wp + i) = h;
    *reinterpret_cast<ush4*>(Wp + NEXP * EMB + i) = m;
    *reinterpret_cast<ush4*>(Wp + 2 * NEXP * EMB + i) = l;
}

// Fully fused: GEMM (split-3 bf16 MFMA) + in-block K-split combine + top-2
// + softmax -> out. R10-R13 plateaued at 81-85 us across four pipeline
// structures => main loop ~ BW floor; the partials round-trip (33 MB write
// + readback + reduce kernel + launch) was the untouched fixed cost.
// Block = 512 thr = 8 waves; wave (g=w>>1, h=w&1): k-split g (KPER=1024),
// tokens h*32..h*32+31 (wave = 32 tok x 64 exp, R12 geometry -> B reads
// shared by 2 A-tiles). LDS 96 KB: sB[4 groups][2 bufs][192][32] -> 1
// block/CU, 8 waves (2/SIMD). K-loop = R12/R13 proven body: counted
// vmcnt(4) (queue entering wait = [A(ks)4, st(ks)6, A(ks+1)4]; retires
// exactly A(ks)+st(ks)), raw s_barrier, 2 named A reg sets (copy-free),
// BK=32 (bank spread at b128 floor: quad=(4lr+lo)&7). Epilogue: fp32
// accH+accL -> LDS logits[4][64][65] (pad 65: conflict-free), fp64 4-way
// combine + bias (= the proven S=4 reduce numerics), 8-part top-2 merge
// (ascending, strict > => lowest index on ties = lax.top_k), softmax,
// direct out write. Precision identical R7-R13 (absmax 0.0).
#define MFMA_BLOCK(BUFC, AH0, AM0, AL0, AH1, AM1, AL1)                          \
    _Pragma("unroll")                                                           \
    for (int et = 0; et < 4; ++et) {                                            \
        const unsigned short* bp = &sB[g][BUFC][et * 16 + lr][lo * 8];          \
        const short8 bH = *reinterpret_cast<const short8*>(bp);                 \
        const short8 bM = *reinterpret_cast<const short8*>(bp + 64 * BK);       \
        const short8 bL = *reinterpret_cast<const short8*>(bp + 128 * BK);      \
        accH[0][et] = __builtin_amdgcn_mfma_f32_16x16x32_bf16(AH0, bH, accH[0][et], 0, 0, 0); \
        accL[0][et] = __builtin_amdgcn_mfma_f32_16x16x32_bf16(AH0, bM, accL[0][et], 0, 0, 0); \
        accL[0][et] = __builtin_amdgcn_mfma_f32_16x16x32_bf16(AM0, bH, accL[0][et], 0, 0, 0); \
        accL[0][et] = __builtin_amdgcn_mfma_f32_16x16x32_bf16(AM0, bM, accL[0][et], 0, 0, 0); \
        accL[0][et] = __builtin_amdgcn_mfma_f32_16x16x32_bf16(AH0, bL, accL[0][et], 0, 0, 0); \
        accL[0][et] = __builtin_amdgcn_mfma_f32_16x16x32_bf16(AL0, bH, accL[0][et], 0, 0, 0); \
        accH[1][et] = __builtin_amdgcn_mfma_f32_16x16x32_bf16(AH1, bH, accH[1][et], 0, 0, 0); \
        accL[1][et] = __builtin_amdgcn_mfma_f32_16x16x32_bf16(AH1, bM, accL[1][et], 0, 0, 0); \
        accL[1][et] = __builtin_amdgcn_mfma_f32_16x16x32_bf16(AM1, bH, accL[1][et], 0, 0, 0); \
        accL[1][et] = __builtin_amdgcn_mfma_f32_16x16x32_bf16(AM1, bM, accL[1][et], 0, 0, 0); \
        accL[1][et] = __builtin_amdgcn_mfma_f32_16x16x32_bf16(AH1, bL, accL[1][et], 0, 0, 0); \
        accL[1][et] = __builtin_amdgcn_mfma_f32_16x16x32_bf16(AL1, bH, accL[1][et], 0, 0, 0); \
    }

#define BODY(KS, AC, BUFC) do {                                                 \
    asm volatile("s_waitcnt vmcnt(4)" ::: "memory");                            \
    __builtin_amdgcn_s_barrier();                                               \
    _Pragma("unroll")                                                           \
    for (int p = 0; p < 6; ++p)                                                 \
        gl_lds16(gb[p] + ((KS) + 1) * BK,                                       \
                 &sB[g][(BUFC) ^ 1][16 * (6 * h + p)][0]);                      \
    __builtin_amdgcn_sched_barrier(0);                                          \
    short8 aH0, aM0, aL0, aH1, aM1, aL1;                                        \
    build_frags(AC[0][0], AC[0][1], aH0, aM0, aL0);                             \
    build_frags(AC[1][0], AC[1][1], aH1, aM1, aL1);                             \
    _Pragma("unroll")                                                           \
    for (int ti = 0; ti < 2; ++ti) {                                            \
        AC[ti][0] = *reinterpret_cast<const float4*>(ax[ti] + ((KS) + 2) * BK);     \
        AC[ti][1] = *reinterpret_cast<const float4*>(ax[ti] + ((KS) + 2) * BK + 4); \
    }                                                                           \
    __builtin_amdgcn_sched_barrier(0);                                          \
    MFMA_BLOCK(BUFC, aH0, aM0, aL0, aH1, aM1, aL1)                              \
} while (0)

__global__ __launch_bounds__(512) void router_fused(
    const float* __restrict__ x, const unsigned short* __restrict__ Wp,
    const float* __restrict__ b, float* __restrict__ out)
{
    __shared__ unsigned short sB[KSP][2][192][BK];   // 96 KB -> 1 block/CU

    const int t  = threadIdx.x;
    const int w  = t >> 6;     // wave 0..7
    const int l  = t & 63;
    const int g  = w >> 1;     // k-split group 0..3
    const int h  = w & 1;      // token half 0/1
    const int lr = l & 15;     // A token-row / B expert-col
    const int lo = l >> 4;     // k-octet selector
    const int tokB = blockIdx.x * 64;
    const int tok0 = tokB + h * 32;
    const int kb   = g * KPER;

    const float* ax[2];
    ax[0] = x + (size_t)(tok0 + lr) * EMB + kb + lo * 8;
    ax[1] = ax[0] + (size_t)16 * EMB;

    // B staging: instr p=0..5 (q=6h+p): LDS rows 16q..16q+15 (16 x 64 B);
    // lane l -> row 16q+(l>>2), 16B piece l&3. Dest linear = lane map.
    const unsigned short* gb[6];
#pragma unroll
    for (int p = 0; p < 6; ++p)
        gb[p] = Wp + (size_t)(16 * (6 * h + p) + (l >> 2)) * EMB + kb + 8 * (l & 3);

    f32x4 accH[2][4], accL[2][4];
#pragma unroll
    for (int ti = 0; ti < 2; ++ti)
#pragma unroll
        for (int et = 0; et < 4; ++et) {
            accH[ti][et] = (f32x4){0.f, 0.f, 0.f, 0.f};
            accL[ti][et] = (f32x4){0.f, 0.f, 0.f, 0.f};
        }

    // prologue FIFO: A(0)(4), st(0)(6), A(1)(4) -> 14 outstanding
    float4 aA[2][2], aB[2][2];
#pragma unroll
    for (int ti = 0; ti < 2; ++ti) {
        aA[ti][0] = *reinterpret_cast<const float4*>(ax[ti]);
        aA[ti][1] = *reinterpret_cast<const float4*>(ax[ti] + 4);
    }
    __builtin_amdgcn_sched_barrier(0);
#pragma unroll
    for (int p = 0; p < 6; ++p)
        gl_lds16(gb[p], &sB[g][0][16 * (6 * h + p)][0]);
    __builtin_amdgcn_sched_barrier(0);
#pragma unroll
    for (int ti = 0; ti < 2; ++ti) {
        aB[ti][0] = *reinterpret_cast<const float4*>(ax[ti] + BK);
        aB[ti][1] = *reinterpret_cast<const float4*>(ax[ti] + BK + 4);
    }
    __builtin_amdgcn_sched_barrier(0);

#pragma unroll 1
    for (int kt = 0; kt < NCH - 2; kt += 2) {
        BODY(kt, aA, 0);
        BODY(kt + 1, aB, 1);
    }
    // peeled ks = NCH-2 (even -> aA, buf0): stage last chunk, no A-issue
    {
        asm volatile("s_waitcnt vmcnt(4)" ::: "memory");
        __builtin_amdgcn_s_barrier();
#pragma unroll
        for (int p = 0; p < 6; ++p)
            gl_lds16(gb[p] + (NCH - 1) * BK, &sB[g][1][16 * (6 * h + p)][0]);
        __builtin_amdgcn_sched_barrier(0);
        short8 aH0, aM0, aL0, aH1, aM1, aL1;
        build_frags(aA[0][0], aA[0][1], aH0, aM0, aL0);
        build_frags(aA[1][0], aA[1][1], aH1, aM1, aL1);
        MFMA_BLOCK(0, aH0, aM0, aL0, aH1, aM1, aL1)
    }
    // peeled ks = NCH-1 (odd -> aB, buf1): drain everything
    {
        asm volatile("s_waitcnt vmcnt(0)" ::: "memory");
        __builtin_amdgcn_s_barrier();
        short8 aH0, aM0, aL0, aH1, aM1, aL1;
        build_frags(aB[0][0], aB[0][1], aH0, aM0, aL0);
        build_frags(aB[1][0], aB[1][1], aH1, aM1, aL1);
        MFMA_BLOCK(1, aH0, aM0, aL0, aH1, aM1, aL1)
    }

    // ---- fused epilogue: in-block 4-split combine + top-2 + softmax ----
    __syncthreads();   // all sB reads done; drains outstanding counters
    float* logits = reinterpret_cast<float*>(&sB[0][0][0][0]); // [4][64][65]
#pragma unroll
    for (int ti = 0; ti < 2; ++ti)
#pragma unroll
        for (int et = 0; et < 4; ++et)
#pragma unroll
            for (int j = 0; j < 4; ++j) {
                const int ltok = h * 32 + ti * 16 + lo * 4 + j;
                logits[(g * 64 + ltok) * 65 + et * 16 + lr]
                    = accH[ti][et][j] + accL[ti][et][j];
            }
    __syncthreads();

    double* sv = reinterpret_cast<double*>(logits + KSP * 64 * 65); // [64][8][2]
    int*    si = reinterpret_cast<int*>(sv + 64 * 8 * 2);           // [64][8][2]

    const int tok  = t >> 3;    // 0..63
    const int part = t & 7;     // 8 experts each
    double v[8];
#pragma unroll
    for (int j = 0; j < 8; ++j) v[j] = 0.0;
#pragma unroll
    for (int gg = 0; gg < KSP; ++gg)
#pragma unroll
        for (int j = 0; j < 8; ++j)
            v[j] += (double)logits[(gg * 64 + tok) * 65 + part * 8 + j];
#pragma unroll
    for (int j = 0; j < 8; ++j) v[j] += (double)b[part * 8 + j];

    double v1 = -1e300, v2 = -1e300; int i1 = 0, i2 = 0;
#pragma unroll
    for (int j = 0; j < 8; ++j) {        // ascending: ties keep lowest idx
        const int e = part * 8 + j;
        if (v[j] > v1)      { v2 = v1; i2 = i1; v1 = v[j]; i1 = e; }
        else if (v[j] > v2) { v2 = v[j]; i2 = e; }
    }
    sv[(tok * 8 + part) * 2 + 0] = v1;
    sv[(tok * 8 + part) * 2 + 1] = v2;
    si[(tok * 8 + part) * 2 + 0] = i1;
    si[(tok * 8 + part) * 2 + 1] = i2;
    __syncthreads();

    if (part == 0) {
        double m1 = -1e300, m2 = -1e300; int j1 = 0, j2 = 0;
#pragma unroll
        for (int p = 0; p < 8; ++p)      // ascending parts: lowest idx on tie
#pragma unroll
            for (int r = 0; r < 2; ++r) {
                const double vv = sv[(tok * 8 + p) * 2 + r];
                const int    ii = si[(tok * 8 + p) * 2 + r];
                if (vv > m1)      { m2 = m1; j2 = j1; m1 = vv; j1 = ii; }
                else if (vv > m2) { m2 = vv; j2 = ii; }
            }
        const float e2  = expf((float)(m2 - m1));   // <= 1
        const float inv = 1.0f / (1.0f + e2);
        const int gt = tokB + tok;
        out[2 * gt]     = (float)j1;
        out[2 * gt + 1] = (float)j2;
        out[2 * TOKENS + 2 * gt]     = inv;
        out[2 * TOKENS + 2 * gt + 1] = e2 * inv;
    }
}

extern "C" void kernel_launch(void* const* d_in, const int* in_sizes, int n_in,
                              void* d_out, int out_size, void* d_ws, size_t ws_size,
                              hipStream_t stream) {
    const float* x = (const float*)d_in[0];
    const float* W = (const float*)d_in[1];
    const float* b = (const float*)d_in[2];
    float* out = (float*)d_out;
    unsigned short* Wp = (unsigned short*)d_ws;   // 1.5 MB, always fits

    split_w<<<dim3(NEXP * EMB / 1024), dim3(256), 0, stream>>>(W, Wp);
    router_fused<<<dim3(TOKENS / 64), dim3(512), 0, stream>>>(x, Wp, b, out);
}